// Round 4
// baseline (117.826 us; speedup 1.0000x reference)
//
#include <hip/hip_runtime.h>

// ---------------------------------------------------------------------------
// PolyDecoder: out[4096,64] = polyfeats(z)[4096,37449] @ W^T + b
// f16 MFMA GEMM, A generated on the fly from registers (branch-free, fully
// unrolled degree-aligned 32-step K-slices), B pre-tiled in workspace.
//
// Padded K layout (32-granular; W padded with zeros):
//   kpad [0,8)=z | 8=const(bias folded) | [9,32)=0 | [32,96)=z^2 |
//   [96,608)=z^3 | [608,4704)=z^4 | [4704,37472)=z^5 | [37472,37504)=0
// step s = kpad/32: 0 deg<=1 | 1..2 deg2 | 3..18 deg3 | 19..146 deg4 |
//                   147..1170 deg5 | 1171 pad (never computed)
//
// Grid: (32 m-blocks of 128 rows) x (37 K-slices):
//   ky in [0,32):  deg5 slice, sbase = 147 + 32*ky   (32 steps, branch-free)
//   ky in [32,36): deg4 slice, sbase = 19 + 32*(ky-32) (32 steps, branch-free)
//   ky == 36:      steps 0..18 (deg 0..3), branchy fallback (1.6% of work)
// Block: 256 thr = 4 waves; wave (g=w>>1, h=w&1) computes rows
//   [g*64, g*64+64) x cols [h*32, h*32+32): 8 mfma_f32_16x16x32_f16 / step.
// ---------------------------------------------------------------------------

#define TOTAL_TERMS 37449
#define NSTEP 1172
#define MBLK 32
#define KY 37

typedef _Float16 half8 __attribute__((ext_vector_type(8)));
typedef float f32x4 __attribute__((ext_vector_type(4)));

// Coalesced tiled transpose W (f32, n-major) -> Wt (f16 fragments).
// Fragment element (s,nt,lane,j) = W[nt*16+(lane&15)][orig(s*32+(lane>>4)*8+j)]
__global__ __launch_bounds__(256) void convert_w(const float* __restrict__ W,
                                                 const float* __restrict__ bias,
                                                 _Float16* __restrict__ Wt) {
    __shared__ _Float16 lds[64][72];
    int tid  = threadIdx.x;
    int lane = tid & 63;
    int nq   = tid >> 6;               // 0..3
    int kb   = blockIdx.x * 64;
    int kp   = kb + lane;

    int o, mode;                       // mode: 0=load W, 1=zero, 2=const+bias
    if (kp < 8)           { o = 1 + kp;            mode = 0; }
    else if (kp == 8)     { o = 0;                 mode = 2; }
    else if (kp < 32)     { o = 0;                 mode = 1; }
    else if (kp < 96)     { o = 9    + (kp - 32);  mode = 0; }
    else if (kp < 608)    { o = 73   + (kp - 96);  mode = 0; }
    else if (kp < 4704)   { o = 585  + (kp - 608); mode = 0; }
    else if (kp < 37472)  { o = 4681 + (kp - 4704);mode = 0; }
    else                  { o = 0;                 mode = 1; }

#pragma unroll
    for (int r = 0; r < 16; ++r) {
        int n = r * 4 + nq;
        const float* wrow = W + (size_t)n * TOTAL_TERMS;
        float v;
        if (mode == 1)      v = 0.f;
        else if (mode == 2) v = wrow[0] + bias[n];
        else                v = wrow[o];             // coalesced along lane
        lds[n][lane] = (_Float16)v;
    }
    __syncthreads();

    int quad = lane >> 4, l16 = lane & 15;
    int n = nq * 16 + l16;
#pragma unroll
    for (int sl = 0; sl < 2; ++sl) {
        int kk = sl * 32 + quad * 8;
        half8 hv;
#pragma unroll
        for (int j = 0; j < 8; ++j) hv[j] = lds[n][kk + j];
        int s = (kb >> 5) + sl;
        *(half8*)(Wt + ((size_t)(s * 4 + nq) * 64 + lane) * 8) = hv;  // coalesced
    }
}

__global__ __launch_bounds__(256, 4) void poly_gemm(const float* __restrict__ z,
                                                    const _Float16* __restrict__ Wt,
                                                    float* __restrict__ out) {
    __shared__ __align__(16) _Float16 zm[128][8];   // sample-major
    __shared__ _Float16 zT[8][144];                 // digit-major (setup reads only)

    int tid  = threadIdx.x;
    int lane = tid & 63;
    int w    = tid >> 6;
    int g    = w >> 1;                 // m-group: rows g*64..g*64+63
    int h    = w & 1;                  // n-group: cols h*32..h*32+31
    int mb   = blockIdx.x;
    int ky   = blockIdx.y;

    if (tid < 128) {
        const float* zp = z + ((size_t)(mb * 128 + tid)) * 8;
        float4 a = *(const float4*)zp;
        float4 b4 = *(const float4*)(zp + 4);
        half8 hz;
        hz[0] = (_Float16)a.x;  hz[1] = (_Float16)a.y;
        hz[2] = (_Float16)a.z;  hz[3] = (_Float16)a.w;
        hz[4] = (_Float16)b4.x; hz[5] = (_Float16)b4.y;
        hz[6] = (_Float16)b4.z; hz[7] = (_Float16)b4.w;
        *(half8*)&zm[tid][0] = hz;
#pragma unroll
        for (int j = 0; j < 8; ++j) zT[j][tid] = hz[j];
    }
    __syncthreads();

    int quad = lane >> 4;
    int l16  = lane & 15;
    int mrow[4];
    half8 zv[4];
    _Float16 zq[4], zq4[4];
#pragma unroll
    for (int t = 0; t < 4; ++t) {
        mrow[t] = g * 64 + t * 16 + l16;
        zv[t]   = *(const half8*)&zm[mrow[t]][0];
        zq[t]   = zT[quad][mrow[t]];       // z[quad]   for this row
        zq4[t]  = zT[quad + 4][mrow[t]];   // z[quad+4]
    }

    f32x4 acc[4][2];
#pragma unroll
    for (int t = 0; t < 4; ++t)
#pragma unroll
        for (int k = 0; k < 2; ++k) acc[t][k] = (f32x4){0.f, 0.f, 0.f, 0.f};

    // B: cols h*32 + k*16 + l16, k in {0,1}; frag (s, ntg=2h+k)
    const _Float16* base = Wt + (size_t)h * 1024 + (size_t)lane * 8;

    auto loadB = [&](int s, half8* B) {
        const _Float16* p = base + (size_t)s * 2048;
        B[0] = *(const half8*)p;
        B[1] = *(const half8*)(p + 512);
    };
    auto mfma8 = [&](const half8* av, const half8* B) {
#pragma unroll
        for (int t = 0; t < 4; ++t)
#pragma unroll
            for (int k = 0; k < 2; ++k)
                acc[t][k] = __builtin_amdgcn_mfma_f32_16x16x32_f16(
                    av[t], B[k], acc[t][k], 0, 0, 0);
    };

    if (ky < 36) {
        // ------- branch-free degree-aligned 32-step slice, fully unrolled ---
        const bool d5 = (ky < 32);
        const int  j  = d5 ? ky : (ky - 32);
        const int  sbase = d5 ? (147 + 32 * j) : (19 + 32 * j);

        _Float16 a1[4];
        if (d5) {
            int r1 = (j >> 2) & 7;                 // z[i1], fixed over slice
#pragma unroll
            for (int t = 0; t < 4; ++t) a1[t] = zT[r1][mrow[t]];
        }

        half8 B0[2], B1[2];
        loadB(sbase, B0);
        loadB(sbase + 1, B1);

#pragma unroll
        for (int h16 = 0; h16 < 2; ++h16) {
            int r2 = (2 * j + h16) & 7;            // changes per 16 steps
            _Float16 gz[4];
#pragma unroll
            for (int t = 0; t < 4; ++t) {
                _Float16 v = zT[r2][mrow[t]];
                gz[t] = d5 ? (_Float16)(a1[t] * v) : v;
            }
#pragma unroll
            for (int i2 = 0; i2 < 16; i2 += 2) {
                int i = h16 * 16 + i2;             // step index in slice (const)
                half8 av[4];
                // even step: digit sel = zq
#pragma unroll
                for (int t = 0; t < 4; ++t) {
                    _Float16 f = gz[t] * zv[t][i2 >> 1] * zq[t];
#pragma unroll
                    for (int e = 0; e < 8; ++e) av[t][e] = zv[t][e] * f;
                }
                mfma8(av, B0);
                if (i + 2 < 32) loadB(sbase + i + 2, B0);
                // odd step: digit sel = zq4
#pragma unroll
                for (int t = 0; t < 4; ++t) {
                    _Float16 f = gz[t] * zv[t][i2 >> 1] * zq4[t];
#pragma unroll
                    for (int e = 0; e < 8; ++e) av[t][e] = zv[t][e] * f;
                }
                mfma8(av, B1);
                if (i + 3 < 32) loadB(sbase + i + 3, B1);
            }
        }
    } else {
        // ------- fallback: steps 0..18 (deg 0,2,3), branchy, 1.6% of work ---
        auto genA = [&](int s, half8* av) {
            if (s == 0) {
#pragma unroll
                for (int t = 0; t < 4; ++t) {
                    if (quad == 0)      av[t] = zv[t];
                    else if (quad == 1) { av[t] = (half8){}; av[t][0] = (_Float16)1.f; }
                    else                av[t] = (half8){};
                }
                return;
            }
            _Float16 f[4];
            if (s >= 3) {                 // deg3: f = z[(u>>1)&7] * z[4*(u&1)+quad]
                int u = s - 3;
                int r1 = (u >> 1) & 7;
                int r2 = ((u & 1) << 2) + quad;
#pragma unroll
                for (int t = 0; t < 4; ++t)
                    f[t] = zT[r1][mrow[t]] * zT[r2][mrow[t]];
            } else {                      // deg2: s in {1,2}
                int r1 = (s - 1) * 4 + quad;
#pragma unroll
                for (int t = 0; t < 4; ++t)
                    f[t] = zT[r1][mrow[t]];
            }
#pragma unroll
            for (int t = 0; t < 4; ++t)
#pragma unroll
                for (int e = 0; e < 8; ++e) av[t][e] = zv[t][e] * f[t];
        };

        half8 B0[2], B1[2];
        loadB(0, B0);
        loadB(1, B1);
        int s = 0;
        for (; s + 1 < 19; s += 2) {
            half8 av[4];
            genA(s, av);
            mfma8(av, B0);
            if (s + 2 < 19) loadB(s + 2, B0);
            genA(s + 1, av);
            mfma8(av, B1);
            if (s + 3 < 19) loadB(s + 3, B1);
        }
        {   // s == 18
            half8 av[4];
            genA(18, av);
            mfma8(av, B0);
        }
    }

    // epilogue: C/D layout col=lane&15, row=(lane>>4)*4+reg
#pragma unroll
    for (int t = 0; t < 4; ++t) {
        int mbase = mb * 128 + g * 64 + t * 16 + quad * 4;
#pragma unroll
        for (int k = 0; k < 2; ++k) {
            int col = h * 32 + k * 16 + l16;
#pragma unroll
            for (int r = 0; r < 4; ++r)
                unsafeAtomicAdd(out + (size_t)(mbase + r) * 64 + col, acc[t][k][r]);
        }
    }
}

extern "C" void kernel_launch(void* const* d_in, const int* in_sizes, int n_in,
                              void* d_out, int out_size, void* d_ws, size_t ws_size,
                              hipStream_t stream) {
    (void)in_sizes; (void)n_in; (void)ws_size;
    const float* z = (const float*)d_in[0];
    const float* W = (const float*)d_in[1];
    const float* b = (const float*)d_in[2];
    float* out = (float*)d_out;
    _Float16* Wt = (_Float16*)d_ws;   // NSTEP*2048*2 = 4,800,512 B

    hipMemsetAsync(d_out, 0, (size_t)out_size * sizeof(float), stream);
    hipLaunchKernelGGL(convert_w, dim3(NSTEP / 2), dim3(256), 0, stream, W, b, Wt);
    hipLaunchKernelGGL(poly_gemm, dim3(MBLK, KY), dim3(256), 0, stream,
                       z, Wt, out);
}

// Round 5
// 95.315 us; speedup vs baseline: 1.2362x; 1.2362x over previous
//
#include <hip/hip_runtime.h>

// ---------------------------------------------------------------------------
// PolyDecoder: out[4096,64] = polyfeats(z)[4096,37449] @ W^T + b
// f16 MFMA GEMM, A generated on the fly from registers, B pre-tiled in ws.
// Round 5: NO ATOMICS — phase-1 writes per-K-slice partial tiles (plain
// streaming stores, each element written once), phase-2 reduces 21 partials.
//
// Padded K layout (32-granular; W padded with zeros):
//   kpad [0,8)=z | 8=const(bias folded) | [9,32)=0 | [32,96)=z^2 |
//   [96,608)=z^3 | [608,4704)=z^4 | [4704,37472)=z^5 | [37472,37504)=0
// step s = kpad/32: 0 deg<=1 | 1..2 deg2 | 3..18 deg3 | 19..146 deg4 |
//                   147..1170 deg5 | 1171 pad (never computed)
//
// Grid: (32 m-blocks of 128 rows) x (KY=21 K-slices):
//   ky in [0,16):  deg5 slice, sbase = 147 + 64*ky, 64 steps, branch-free
//   ky in [16,20): deg4 slice, sbase = 19 + 32*(ky-16), 32 steps, branch-free
//   ky == 20:      steps 0..18 (deg 0..3), branchy fallback
// Block: 256 thr = 4 waves; wave (g=w>>1, h=w&1): rows [g*64,g*64+64) x
//   cols [h*32,h*32+32): 8 mfma_f32_16x16x32_f16 / step.
// ---------------------------------------------------------------------------

#define TOTAL_TERMS 37449
#define NSTEP 1172
#define MBLK 32
#define KY 21
#define OUT_ELEMS 262144            // 4096*64

typedef _Float16 half8 __attribute__((ext_vector_type(8)));
typedef float f32x4 __attribute__((ext_vector_type(4)));

// Coalesced tiled transpose W (f32, n-major) -> Wt (f16 fragments).
// Fragment element (s,nt,lane,j) = W[nt*16+(lane&15)][orig(s*32+(lane>>4)*8+j)]
__global__ __launch_bounds__(256) void convert_w(const float* __restrict__ W,
                                                 const float* __restrict__ bias,
                                                 _Float16* __restrict__ Wt) {
    __shared__ _Float16 lds[64][72];
    int tid  = threadIdx.x;
    int lane = tid & 63;
    int nq   = tid >> 6;               // 0..3
    int kb   = blockIdx.x * 64;
    int kp   = kb + lane;

    int o, mode;                       // mode: 0=load W, 1=zero, 2=const+bias
    if (kp < 8)           { o = 1 + kp;            mode = 0; }
    else if (kp == 8)     { o = 0;                 mode = 2; }
    else if (kp < 32)     { o = 0;                 mode = 1; }
    else if (kp < 96)     { o = 9    + (kp - 32);  mode = 0; }
    else if (kp < 608)    { o = 73   + (kp - 96);  mode = 0; }
    else if (kp < 4704)   { o = 585  + (kp - 608); mode = 0; }
    else if (kp < 37472)  { o = 4681 + (kp - 4704);mode = 0; }
    else                  { o = 0;                 mode = 1; }

#pragma unroll
    for (int r = 0; r < 16; ++r) {
        int n = r * 4 + nq;
        const float* wrow = W + (size_t)n * TOTAL_TERMS;
        float v;
        if (mode == 1)      v = 0.f;
        else if (mode == 2) v = wrow[0] + bias[n];
        else                v = wrow[o];             // coalesced along lane
        lds[n][lane] = (_Float16)v;
    }
    __syncthreads();

    int quad = lane >> 4, l16 = lane & 15;
    int n = nq * 16 + l16;
#pragma unroll
    for (int sl = 0; sl < 2; ++sl) {
        int kk = sl * 32 + quad * 8;
        half8 hv;
#pragma unroll
        for (int j = 0; j < 8; ++j) hv[j] = lds[n][kk + j];
        int s = (kb >> 5) + sl;
        *(half8*)(Wt + ((size_t)(s * 4 + nq) * 64 + lane) * 8) = hv;  // coalesced
    }
}

__global__ __launch_bounds__(256, 4) void poly_gemm(const float* __restrict__ z,
                                                    const _Float16* __restrict__ Wt,
                                                    float* __restrict__ part,
                                                    float* __restrict__ out,
                                                    int use_atomic) {
    __shared__ __align__(16) _Float16 zm[128][8];   // sample-major
    __shared__ _Float16 zT[8][144];                 // digit-major (setup reads only)

    int tid  = threadIdx.x;
    int lane = tid & 63;
    int w    = tid >> 6;
    int g    = w >> 1;                 // m-group: rows g*64..g*64+63
    int h    = w & 1;                  // n-group: cols h*32..h*32+31
    int mb   = blockIdx.x;
    int ky   = blockIdx.y;

    if (tid < 128) {
        const float* zp = z + ((size_t)(mb * 128 + tid)) * 8;
        float4 a = *(const float4*)zp;
        float4 b4 = *(const float4*)(zp + 4);
        half8 hz;
        hz[0] = (_Float16)a.x;  hz[1] = (_Float16)a.y;
        hz[2] = (_Float16)a.z;  hz[3] = (_Float16)a.w;
        hz[4] = (_Float16)b4.x; hz[5] = (_Float16)b4.y;
        hz[6] = (_Float16)b4.z; hz[7] = (_Float16)b4.w;
        *(half8*)&zm[tid][0] = hz;
#pragma unroll
        for (int j = 0; j < 8; ++j) zT[j][tid] = hz[j];
    }
    __syncthreads();

    int quad = lane >> 4;
    int l16  = lane & 15;
    int mrow[4];
    half8 zv[4];
    _Float16 zq[4], zq4[4];
#pragma unroll
    for (int t = 0; t < 4; ++t) {
        mrow[t] = g * 64 + t * 16 + l16;
        zv[t]   = *(const half8*)&zm[mrow[t]][0];
        zq[t]   = zT[quad][mrow[t]];       // z[quad]
        zq4[t]  = zT[quad + 4][mrow[t]];   // z[quad+4]
    }

    f32x4 acc[4][2];
#pragma unroll
    for (int t = 0; t < 4; ++t)
#pragma unroll
        for (int k = 0; k < 2; ++k) acc[t][k] = (f32x4){0.f, 0.f, 0.f, 0.f};

    const _Float16* base = Wt + (size_t)h * 1024 + (size_t)lane * 8;

    auto loadB = [&](int s, half8* B) {
        const _Float16* p = base + (size_t)s * 2048;
        B[0] = *(const half8*)p;
        B[1] = *(const half8*)(p + 512);
    };
    auto mfma8 = [&](const half8* av, const half8* B) {
#pragma unroll
        for (int t = 0; t < 4; ++t)
#pragma unroll
            for (int k = 0; k < 2; ++k)
                acc[t][k] = __builtin_amdgcn_mfma_f32_16x16x32_f16(
                    av[t], B[k], acc[t][k], 0, 0, 0);
    };

    if (ky < 20) {
        // ---- branch-free degree-aligned slice (nh16 x 16 steps) ----
        const bool d5 = (ky < 16);
        const int  nh16   = d5 ? 4 : 2;
        const int  sbase  = d5 ? (147 + 64 * ky) : (19 + 32 * (ky - 16));
        const int  r2base = d5 ? (4 * ky) : (2 * (ky - 16));

        _Float16 a1[4];
        if (d5) {
            int r1 = (ky >> 1) & 7;                // z[i1], fixed over slice
#pragma unroll
            for (int t = 0; t < 4; ++t) a1[t] = zT[r1][mrow[t]];
        }

        half8 B0[2], B1[2];
        loadB(sbase, B0);
        loadB(sbase + 1, B1);

        for (int h16 = 0; h16 < nh16; ++h16) {
            int r2 = (r2base + h16) & 7;
            _Float16 gz[4];
#pragma unroll
            for (int t = 0; t < 4; ++t) {
                _Float16 v = zT[r2][mrow[t]];
                gz[t] = d5 ? (_Float16)(a1[t] * v) : v;
            }
            int sh = sbase + h16 * 16;
#pragma unroll
            for (int i2 = 0; i2 < 16; i2 += 2) {
                half8 av[4];
#pragma unroll
                for (int t = 0; t < 4; ++t) {
                    _Float16 f = gz[t] * zv[t][i2 >> 1] * zq[t];
#pragma unroll
                    for (int e = 0; e < 8; ++e) av[t][e] = zv[t][e] * f;
                }
                mfma8(av, B0);
                loadB(sh + i2 + 2, B0);   // unconditional; Wt padded +2 steps
#pragma unroll
                for (int t = 0; t < 4; ++t) {
                    _Float16 f = gz[t] * zv[t][i2 >> 1] * zq4[t];
#pragma unroll
                    for (int e = 0; e < 8; ++e) av[t][e] = zv[t][e] * f;
                }
                mfma8(av, B1);
                loadB(sh + i2 + 3, B1);
            }
        }
    } else {
        // ---- fallback: steps 0..18 (deg 0,2,3) ----
        auto genA = [&](int s, half8* av) {
            if (s == 0) {
#pragma unroll
                for (int t = 0; t < 4; ++t) {
                    if (quad == 0)      av[t] = zv[t];
                    else if (quad == 1) { av[t] = (half8){}; av[t][0] = (_Float16)1.f; }
                    else                av[t] = (half8){};
                }
                return;
            }
            _Float16 f[4];
            if (s >= 3) {
                int u = s - 3;
                int r1 = (u >> 1) & 7;
                int r2 = ((u & 1) << 2) + quad;
#pragma unroll
                for (int t = 0; t < 4; ++t)
                    f[t] = zT[r1][mrow[t]] * zT[r2][mrow[t]];
            } else {
                int r1 = (s - 1) * 4 + quad;
#pragma unroll
                for (int t = 0; t < 4; ++t)
                    f[t] = zT[r1][mrow[t]];
            }
#pragma unroll
            for (int t = 0; t < 4; ++t)
#pragma unroll
                for (int e = 0; e < 8; ++e) av[t][e] = zv[t][e] * f[t];
        };

        half8 B0[2], B1[2];
        loadB(0, B0);
        loadB(1, B1);
        int s = 0;
        for (; s + 1 < 19; s += 2) {
            half8 av[4];
            genA(s, av);
            mfma8(av, B0);
            if (s + 2 < 19) loadB(s + 2, B0);
            genA(s + 1, av);
            mfma8(av, B1);
            if (s + 3 < 19) loadB(s + 3, B1);
        }
        {   // s == 18
            half8 av[4];
            genA(18, av);
            mfma8(av, B0);
        }
    }

    // epilogue: C/D layout col=lane&15, row=(lane>>4)*4+reg
    float* dstbase = use_atomic ? out : (part + (size_t)ky * OUT_ELEMS);
#pragma unroll
    for (int t = 0; t < 4; ++t) {
        int mbase = mb * 128 + g * 64 + t * 16 + quad * 4;
#pragma unroll
        for (int k = 0; k < 2; ++k) {
            int col = h * 32 + k * 16 + l16;
#pragma unroll
            for (int r = 0; r < 4; ++r) {
                size_t idx = (size_t)(mbase + r) * 64 + col;
                if (use_atomic) unsafeAtomicAdd(dstbase + idx, acc[t][k][r]);
                else            dstbase[idx] = acc[t][k][r];
            }
        }
    }
}

// Phase 2: out[i] = sum_ky part[ky][i]  (vectorized float4)
__global__ __launch_bounds__(256) void reduce_part(const float* __restrict__ part,
                                                   float* __restrict__ out) {
    int gid = blockIdx.x * 256 + threadIdx.x;      // 65536 float4s
    const f32x4* p4 = (const f32x4*)part;
    f32x4 s = (f32x4){0.f, 0.f, 0.f, 0.f};
#pragma unroll
    for (int j = 0; j < KY; ++j)
        s += p4[(size_t)j * (OUT_ELEMS / 4) + gid];
    ((f32x4*)out)[gid] = s;
}

extern "C" void kernel_launch(void* const* d_in, const int* in_sizes, int n_in,
                              void* d_out, int out_size, void* d_ws, size_t ws_size,
                              hipStream_t stream) {
    (void)in_sizes; (void)n_in;
    const float* z = (const float*)d_in[0];
    const float* W = (const float*)d_in[1];
    const float* b = (const float*)d_in[2];
    float* out = (float*)d_out;

    const size_t part_bytes = (size_t)KY * OUT_ELEMS * sizeof(float);  // 22 MB
    const size_t wt_bytes   = (size_t)(NSTEP + 2) * 2048 * sizeof(_Float16);
    const bool two_phase = ws_size >= part_bytes + wt_bytes;

    float* part;
    _Float16* Wt;
    if (two_phase) {
        part = (float*)d_ws;
        Wt   = (_Float16*)((char*)d_ws + part_bytes);
    } else {
        part = out;                    // unused in atomic mode
        Wt   = (_Float16*)d_ws;
    }

    if (!two_phase)
        hipMemsetAsync(d_out, 0, (size_t)out_size * sizeof(float), stream);
    hipLaunchKernelGGL(convert_w, dim3(NSTEP / 2), dim3(256), 0, stream, W, b, Wt);
    hipLaunchKernelGGL(poly_gemm, dim3(MBLK, KY), dim3(256), 0, stream,
                       z, Wt, part, out, two_phase ? 0 : 1);
    if (two_phase)
        hipLaunchKernelGGL(reduce_part, dim3(OUT_ELEMS / 4 / 256), dim3(256), 0,
                           stream, part, out);
}